// Round 1
// baseline (1949.278 us; speedup 1.0000x reference)
//
#include <hip/hip_runtime.h>
#include <hip/hip_bf16.h>

// RGCN 2-layer, basis-decomposed. f32 vector math throughout (round 0 baseline).
//
// z[n, b*128+d] = sum_{edges e -> n} (a[et_e,b] / cnt[et_e,n]) * x[src_e, d]
// out[n, :]    = z[n, :] @ Vflat[1024, Dout] + x[n, :] @ root + bias
// layer1: relu -> h ; layer2: softmax -> d_out

constexpr int TD   = 128;        // feature dim (both layers' input dim)
constexpr int TB   = 8;          // bases
constexpr int TK   = TB * TD;    // 1024 = basis-concat K
constexpr int TNB  = 32;         // nodes per block in layer kernel
constexpr int ZSTR = TK + 4;     // 1028: LDS stride for z (bank-spread, 16B-aligned)
constexpr int XSTR = TD + 4;     // 132:  LDS stride for x tile

__global__ void k_hist(const int* __restrict__ ei, const int* __restrict__ et,
                       int* __restrict__ deg, int* __restrict__ cnt2,
                       int E, int N) {
  int e = blockIdx.x * 256 + threadIdx.x;
  if (e >= E) return;
  int d = ei[E + e];          // dst
  int r = et[e];
  atomicAdd(&deg[d], 1);
  atomicAdd(&cnt2[r * N + d], 1);
}

// single-block exclusive prefix sum of deg -> off (and cursor copy); off[n]=E
__global__ void k_scan(const int* __restrict__ deg, int* __restrict__ off,
                       int* __restrict__ cursor, int n, int total) {
  __shared__ int sh[1024];
  __shared__ int carry_s;
  const int t = threadIdx.x;
  if (t == 0) carry_s = 0;
  __syncthreads();
  for (int base = 0; base < n; base += 1024) {
    int i = base + t;
    int v = (i < n) ? deg[i] : 0;
    sh[t] = v;
    __syncthreads();
    for (int d = 1; d < 1024; d <<= 1) {
      int add = (t >= d) ? sh[t - d] : 0;
      __syncthreads();
      sh[t] += add;
      __syncthreads();
    }
    int incl = sh[t];
    int carry = carry_s;
    if (i < n) { int ex = carry + incl - v; off[i] = ex; cursor[i] = ex; }
    __syncthreads();
    if (t == 1023) carry_s = carry + sh[1023];
    __syncthreads();
  }
  if (t == 0) off[n] = total;
}

__global__ void k_scatter(const int* __restrict__ ei, const int* __restrict__ et,
                          int* __restrict__ cursor, const int* __restrict__ cnt2,
                          int* __restrict__ packed, float* __restrict__ invc,
                          int E, int N) {
  int e = blockIdx.x * 256 + threadIdx.x;
  if (e >= E) return;
  int s = ei[e], d = ei[E + e], r = et[e];
  int p = atomicAdd(&cursor[d], 1);
  packed[p] = s | (r << 17);                 // src < 2^17, et < 32
  invc[p] = 1.0f / (float)cnt2[r * N + d];   // cnt >= 1 wherever an edge exists
}

template <int DOUT, bool RELU, bool SOFTMAX>
__global__ __launch_bounds__(256, 1) void k_layer(
    const float* __restrict__ in, const float* __restrict__ Vc,
    const float* __restrict__ a, const float* __restrict__ root,
    const float* __restrict__ bias, const int* __restrict__ off,
    const int* __restrict__ packed, const float* __restrict__ invc,
    float* __restrict__ out, int Ntot) {
  extern __shared__ float smem[];
  float* z  = smem;                    // [TNB][ZSTR]
  float* xl = z + TNB * ZSTR;          // [TNB][XSTR]
  float* al = xl + TNB * XSTR;         // [256] = a[R][B]
  const int t = threadIdx.x;
  const int n0 = blockIdx.x * TNB;

  al[t] = a[t];   // R*B == 256 == blockDim
  // stage x tile (also used for root-term GEMM)
  for (int i = t; i < TNB * (TD / 4); i += 256) {
    int row = i >> 5;            // TD/4 == 32
    int c4 = (i & 31) * 4;
    int n = n0 + row;
    float4 v = make_float4(0.f, 0.f, 0.f, 0.f);
    if (n < Ntot) v = *reinterpret_cast<const float4*>(in + (size_t)n * TD + c4);
    *reinterpret_cast<float4*>(xl + row * XSTR + c4) = v;
  }
  __syncthreads();

  // ---- phase 1: per-wave edge aggregation into z ----
  {
    const int wv = t >> 6, lane = t & 63;
    for (int nn = wv * 8; nn < wv * 8 + 8; ++nn) {
      int n = n0 + nn;
      float zacc[16];
#pragma unroll
      for (int j = 0; j < 16; ++j) zacc[j] = 0.f;
      if (n < Ntot) {
        int e1 = off[n + 1];
        for (int e = off[n]; e < e1; ++e) {
          int pk = packed[e];
          float iv = invc[e];
          int s = pk & 131071;
          int r = pk >> 17;
          float xv0 = in[(size_t)s * TD + lane];
          float xv1 = in[(size_t)s * TD + 64 + lane];
          const float* ar = al + r * TB;
#pragma unroll
          for (int b = 0; b < TB; ++b) {
            float c = ar[b] * iv;
            zacc[2 * b]     += c * xv0;
            zacc[2 * b + 1] += c * xv1;
          }
        }
      }
      float* zr = z + nn * ZSTR;
#pragma unroll
      for (int b = 0; b < TB; ++b) {
        zr[b * TD + lane]      = zacc[2 * b];
        zr[b * TD + 64 + lane] = zacc[2 * b + 1];
      }
    }
  }
  __syncthreads();

  // ---- phase 2: [TNB, TK] @ [TK, DOUT] + [TNB, TD] @ root + bias ----
  if constexpr (DOUT == 128) {
    const int tx = t & 31, ty = t >> 5;
    const int oc = tx * 4;
    float4 acc[4];
#pragma unroll
    for (int i = 0; i < 4; ++i) acc[i] = make_float4(0.f, 0.f, 0.f, 0.f);
#pragma unroll 4
    for (int k = 0; k < TK; ++k) {
      float4 vr = *reinterpret_cast<const float4*>(Vc + (size_t)k * 128 + oc);
#pragma unroll
      for (int i = 0; i < 4; ++i) {
        float zv = z[(ty * 4 + i) * ZSTR + k];
        acc[i].x += zv * vr.x; acc[i].y += zv * vr.y;
        acc[i].z += zv * vr.z; acc[i].w += zv * vr.w;
      }
    }
#pragma unroll 4
    for (int k = 0; k < TD; ++k) {
      float4 vr = *reinterpret_cast<const float4*>(root + (size_t)k * 128 + oc);
#pragma unroll
      for (int i = 0; i < 4; ++i) {
        float xv = xl[(ty * 4 + i) * XSTR + k];
        acc[i].x += xv * vr.x; acc[i].y += xv * vr.y;
        acc[i].z += xv * vr.z; acc[i].w += xv * vr.w;
      }
    }
    float4 bb = *reinterpret_cast<const float4*>(bias + oc);
#pragma unroll
    for (int i = 0; i < 4; ++i) {
      int n = n0 + ty * 4 + i;
      if (n < Ntot) {
        float4 r = acc[i];
        r.x += bb.x; r.y += bb.y; r.z += bb.z; r.w += bb.w;
        if (RELU) {
          r.x = fmaxf(r.x, 0.f); r.y = fmaxf(r.y, 0.f);
          r.z = fmaxf(r.z, 0.f); r.w = fmaxf(r.w, 0.f);
        }
        *reinterpret_cast<float4*>(out + (size_t)n * 128 + oc) = r;
      }
    }
  } else {  // DOUT == 32
    const int tx = t & 7, ty = t >> 3;
    const int oc = tx * 4;
    float4 acc = make_float4(0.f, 0.f, 0.f, 0.f);
#pragma unroll 4
    for (int k = 0; k < TK; ++k) {
      float4 vr = *reinterpret_cast<const float4*>(Vc + (size_t)k * DOUT + oc);
      float zv = z[ty * ZSTR + k];
      acc.x += zv * vr.x; acc.y += zv * vr.y; acc.z += zv * vr.z; acc.w += zv * vr.w;
    }
#pragma unroll 4
    for (int k = 0; k < TD; ++k) {
      float4 vr = *reinterpret_cast<const float4*>(root + (size_t)k * DOUT + oc);
      float xv = xl[ty * XSTR + k];
      acc.x += xv * vr.x; acc.y += xv * vr.y; acc.z += xv * vr.z; acc.w += xv * vr.w;
    }
    float4 bb = *reinterpret_cast<const float4*>(bias + oc);
    acc.x += bb.x; acc.y += bb.y; acc.z += bb.z; acc.w += bb.w;
    if constexpr (SOFTMAX) {
      float m = fmaxf(fmaxf(acc.x, acc.y), fmaxf(acc.z, acc.w));
      m = fmaxf(m, __shfl_xor(m, 1));
      m = fmaxf(m, __shfl_xor(m, 2));
      m = fmaxf(m, __shfl_xor(m, 4));
      float e0 = __expf(acc.x - m), e1 = __expf(acc.y - m);
      float e2 = __expf(acc.z - m), e3 = __expf(acc.w - m);
      float s = e0 + e1 + e2 + e3;
      s += __shfl_xor(s, 1); s += __shfl_xor(s, 2); s += __shfl_xor(s, 4);
      float is = 1.f / s;
      acc = make_float4(e0 * is, e1 * is, e2 * is, e3 * is);
    }
    int n = n0 + ty;
    if (n < Ntot) *reinterpret_cast<float4*>(out + (size_t)n * DOUT + oc) = acc;
  }
}

extern "C" void kernel_launch(void* const* d_in, const int* in_sizes, int n_in,
                              void* d_out, int out_size, void* d_ws, size_t ws_size,
                              hipStream_t stream) {
  const float* x     = (const float*)d_in[0];
  const float* V1    = (const float*)d_in[1];
  const float* a1    = (const float*)d_in[2];
  const float* root1 = (const float*)d_in[3];
  const float* bias1 = (const float*)d_in[4];
  const float* V2    = (const float*)d_in[5];
  const float* a2    = (const float*)d_in[6];
  const float* root2 = (const float*)d_in[7];
  const float* bias2 = (const float*)d_in[8];
  const int*   ei    = (const int*)d_in[9];    // [2, E]
  const int*   et    = (const int*)d_in[10];   // [E]

  const int N = in_sizes[0] / TD;
  const int E = in_sizes[10];
  const int R = 32;

  char* w = (char*)d_ws;
  auto alloc = [&](size_t bytes) {
    char* p = w;
    w += (bytes + 255) & ~(size_t)255;
    return p;
  };
  int*   off    = (int*)alloc((size_t)(N + 1) * 4);
  int*   cursor = (int*)alloc((size_t)N * 4);
  int*   deg    = (int*)alloc((size_t)N * 4);
  int*   cnt2   = (int*)alloc((size_t)R * N * 4);
  int*   packed = (int*)alloc((size_t)E * 4);
  float* invc   = (float*)alloc((size_t)E * 4);
  float* h      = (float*)alloc((size_t)N * TD * 4);

  hipMemsetAsync(deg, 0, (size_t)N * 4, stream);
  hipMemsetAsync(cnt2, 0, (size_t)R * N * 4, stream);

  int egrid = (E + 255) / 256;
  k_hist<<<egrid, 256, 0, stream>>>(ei, et, deg, cnt2, E, N);
  k_scan<<<1, 1024, 0, stream>>>(deg, off, cursor, N, E);
  k_scatter<<<egrid, 256, 0, stream>>>(ei, et, cursor, cnt2, packed, invc, E, N);

  const size_t shmem = (size_t)(TNB * ZSTR + TNB * XSTR + 256) * sizeof(float);
  hipFuncSetAttribute(reinterpret_cast<const void*>(&k_layer<128, true, false>),
                      hipFuncAttributeMaxDynamicSharedMemorySize, (int)shmem);
  hipFuncSetAttribute(reinterpret_cast<const void*>(&k_layer<32, false, true>),
                      hipFuncAttributeMaxDynamicSharedMemorySize, (int)shmem);

  int ngrid = (N + TNB - 1) / TNB;
  k_layer<128, true, false><<<ngrid, 256, shmem, stream>>>(
      x, V1, a1, root1, bias1, off, packed, invc, h, N);
  k_layer<32, false, true><<<ngrid, 256, shmem, stream>>>(
      h, V2, a2, root2, bias2, off, packed, invc, (float*)d_out, N);
}

// Round 2
// 1438.084 us; speedup vs baseline: 1.3555x; 1.3555x over previous
//
#include <hip/hip_runtime.h>
#include <hip/hip_bf16.h>

// RGCN 2-layer, basis-decomposed. f32 vector math.
// R1: TNB 32->16, BLOCK 256->512, float4 K-chunks in phase 2.
// LDS/block = 75.3 KB -> 2 blocks/CU -> 16 waves/CU (4/SIMD).

constexpr int TD   = 128;        // feature dim (both layers' input dim)
constexpr int TB   = 8;          // bases
constexpr int TK   = TB * TD;    // 1024 = basis-concat K
constexpr int TNB  = 16;         // nodes per block in layer kernel
constexpr int BLK  = 512;        // threads per block (8 waves)
constexpr int ZSTR = TK + 4;     // 1028: LDS stride for z (16B-aligned)
constexpr int XSTR = TD + 4;     // 132:  LDS stride for x tile

__global__ void k_hist(const int* __restrict__ ei, const int* __restrict__ et,
                       int* __restrict__ deg, int* __restrict__ cnt2,
                       int E, int N) {
  int e = blockIdx.x * 256 + threadIdx.x;
  if (e >= E) return;
  int d = ei[E + e];          // dst
  int r = et[e];
  atomicAdd(&deg[d], 1);
  atomicAdd(&cnt2[r * N + d], 1);
}

// single-block exclusive prefix sum of deg -> off (and cursor copy); off[n]=E
__global__ void k_scan(const int* __restrict__ deg, int* __restrict__ off,
                       int* __restrict__ cursor, int n, int total) {
  __shared__ int sh[1024];
  __shared__ int carry_s;
  const int t = threadIdx.x;
  if (t == 0) carry_s = 0;
  __syncthreads();
  for (int base = 0; base < n; base += 1024) {
    int i = base + t;
    int v = (i < n) ? deg[i] : 0;
    sh[t] = v;
    __syncthreads();
    for (int d = 1; d < 1024; d <<= 1) {
      int add = (t >= d) ? sh[t - d] : 0;
      __syncthreads();
      sh[t] += add;
      __syncthreads();
    }
    int incl = sh[t];
    int carry = carry_s;
    if (i < n) { int ex = carry + incl - v; off[i] = ex; cursor[i] = ex; }
    __syncthreads();
    if (t == 1023) carry_s = carry + sh[1023];
    __syncthreads();
  }
  if (t == 0) off[n] = total;
}

__global__ void k_scatter(const int* __restrict__ ei, const int* __restrict__ et,
                          int* __restrict__ cursor, const int* __restrict__ cnt2,
                          int* __restrict__ packed, float* __restrict__ invc,
                          int E, int N) {
  int e = blockIdx.x * 256 + threadIdx.x;
  if (e >= E) return;
  int s = ei[e], d = ei[E + e], r = et[e];
  int p = atomicAdd(&cursor[d], 1);
  packed[p] = s | (r << 17);                 // src < 2^17, et < 32
  invc[p] = 1.0f / (float)cnt2[r * N + d];   // cnt >= 1 wherever an edge exists
}

template <int DOUT, bool RELU, bool SOFTMAX>
__global__ __launch_bounds__(BLK, 4) void k_layer(
    const float* __restrict__ in, const float* __restrict__ Vc,
    const float* __restrict__ a, const float* __restrict__ root,
    const float* __restrict__ bias, const int* __restrict__ off,
    const int* __restrict__ packed, const float* __restrict__ invc,
    float* __restrict__ out, int Ntot) {
  extern __shared__ float smem[];
  float* z  = smem;                    // [TNB][ZSTR]
  float* xl = z + TNB * ZSTR;          // [TNB][XSTR]
  float* al = xl + TNB * XSTR;         // [256] = a[R][B]
  const int t = threadIdx.x;
  const int n0 = blockIdx.x * TNB;

  if (t < 256) al[t] = a[t];
  // stage x tile (also used for root-term GEMM); TNB*32 == BLK
  {
    int row = t >> 5;
    int c4 = (t & 31) * 4;
    int n = n0 + row;
    float4 v = make_float4(0.f, 0.f, 0.f, 0.f);
    if (n < Ntot) v = *reinterpret_cast<const float4*>(in + (size_t)n * TD + c4);
    *reinterpret_cast<float4*>(xl + row * XSTR + c4) = v;
  }
  __syncthreads();

  // ---- phase 1: per-wave edge aggregation into z (2 nodes / wave) ----
  {
    const int wv = t >> 6, lane = t & 63;
    for (int nn = wv * 2; nn < wv * 2 + 2; ++nn) {
      int n = n0 + nn;
      float zacc[16];
#pragma unroll
      for (int j = 0; j < 16; ++j) zacc[j] = 0.f;
      if (n < Ntot) {
        int e1 = off[n + 1];
        for (int e = off[n]; e < e1; ++e) {
          int pk = packed[e];
          float iv = invc[e];
          int s = pk & 131071;
          int r = pk >> 17;
          float xv0 = in[(size_t)s * TD + lane];
          float xv1 = in[(size_t)s * TD + 64 + lane];
          const float* ar = al + r * TB;
#pragma unroll
          for (int b = 0; b < TB; ++b) {
            float c = ar[b] * iv;
            zacc[2 * b]     += c * xv0;
            zacc[2 * b + 1] += c * xv1;
          }
        }
      }
      float* zr = z + nn * ZSTR;
#pragma unroll
      for (int b = 0; b < TB; ++b) {
        zr[b * TD + lane]      = zacc[2 * b];
        zr[b * TD + 64 + lane] = zacc[2 * b + 1];
      }
    }
  }
  __syncthreads();

  // ---- phase 2: [TNB, TK] @ [TK, DOUT] + [TNB, TD] @ root + bias ----
  if constexpr (DOUT == 128) {
    const int tx = t & 31, ty = t >> 5;     // ty 0..15 = node row
    const int oc = tx * 4;
    const float* zrow = z + ty * ZSTR;
    const float* xrow = xl + ty * XSTR;
    float4 acc = make_float4(0.f, 0.f, 0.f, 0.f);
#pragma unroll 2
    for (int k = 0; k < TK; k += 4) {
      float4 zv = *reinterpret_cast<const float4*>(zrow + k);
      const float* vp = Vc + (size_t)k * 128 + oc;
      float4 v0 = *reinterpret_cast<const float4*>(vp);
      float4 v1 = *reinterpret_cast<const float4*>(vp + 128);
      float4 v2 = *reinterpret_cast<const float4*>(vp + 256);
      float4 v3 = *reinterpret_cast<const float4*>(vp + 384);
      acc.x += zv.x * v0.x + zv.y * v1.x + zv.z * v2.x + zv.w * v3.x;
      acc.y += zv.x * v0.y + zv.y * v1.y + zv.z * v2.y + zv.w * v3.y;
      acc.z += zv.x * v0.z + zv.y * v1.z + zv.z * v2.z + zv.w * v3.z;
      acc.w += zv.x * v0.w + zv.y * v1.w + zv.z * v2.w + zv.w * v3.w;
    }
#pragma unroll 2
    for (int k = 0; k < TD; k += 4) {
      float4 xv = *reinterpret_cast<const float4*>(xrow + k);
      const float* vp = root + (size_t)k * 128 + oc;
      float4 v0 = *reinterpret_cast<const float4*>(vp);
      float4 v1 = *reinterpret_cast<const float4*>(vp + 128);
      float4 v2 = *reinterpret_cast<const float4*>(vp + 256);
      float4 v3 = *reinterpret_cast<const float4*>(vp + 384);
      acc.x += xv.x * v0.x + xv.y * v1.x + xv.z * v2.x + xv.w * v3.x;
      acc.y += xv.x * v0.y + xv.y * v1.y + xv.z * v2.y + xv.w * v3.y;
      acc.z += xv.x * v0.z + xv.y * v1.z + xv.z * v2.z + xv.w * v3.z;
      acc.w += xv.x * v0.w + xv.y * v1.w + xv.z * v2.w + xv.w * v3.w;
    }
    float4 bb = *reinterpret_cast<const float4*>(bias + oc);
    int n = n0 + ty;
    if (n < Ntot) {
      float4 r = acc;
      r.x += bb.x; r.y += bb.y; r.z += bb.z; r.w += bb.w;
      if (RELU) {
        r.x = fmaxf(r.x, 0.f); r.y = fmaxf(r.y, 0.f);
        r.z = fmaxf(r.z, 0.f); r.w = fmaxf(r.w, 0.f);
      }
      *reinterpret_cast<float4*>(out + (size_t)n * 128 + oc) = r;
    }
  } else {  // DOUT == 32: one scalar output per thread
    const int o = t & 31, ty = t >> 5;      // ty 0..15
    const float* zrow = z + ty * ZSTR;
    const float* xrow = xl + ty * XSTR;
    float acc = 0.f;
#pragma unroll 2
    for (int k = 0; k < TK; k += 4) {
      float4 zv = *reinterpret_cast<const float4*>(zrow + k);
      const float* vp = Vc + (size_t)k * DOUT + o;
      acc += zv.x * vp[0] + zv.y * vp[DOUT] + zv.z * vp[2 * DOUT] + zv.w * vp[3 * DOUT];
    }
#pragma unroll 2
    for (int k = 0; k < TD; k += 4) {
      float4 xv = *reinterpret_cast<const float4*>(xrow + k);
      const float* vp = root + (size_t)k * DOUT + o;
      acc += xv.x * vp[0] + xv.y * vp[DOUT] + xv.z * vp[2 * DOUT] + xv.w * vp[3 * DOUT];
    }
    acc += bias[o];
    if constexpr (SOFTMAX) {
      float m = acc;
      m = fmaxf(m, __shfl_xor(m, 1));
      m = fmaxf(m, __shfl_xor(m, 2));
      m = fmaxf(m, __shfl_xor(m, 4));
      m = fmaxf(m, __shfl_xor(m, 8));
      m = fmaxf(m, __shfl_xor(m, 16));
      float ev = __expf(acc - m);
      float s = ev;
      s += __shfl_xor(s, 1); s += __shfl_xor(s, 2); s += __shfl_xor(s, 4);
      s += __shfl_xor(s, 8); s += __shfl_xor(s, 16);
      acc = ev / s;
    }
    int n = n0 + ty;
    if (n < Ntot) out[(size_t)n * DOUT + o] = acc;
  }
}

extern "C" void kernel_launch(void* const* d_in, const int* in_sizes, int n_in,
                              void* d_out, int out_size, void* d_ws, size_t ws_size,
                              hipStream_t stream) {
  const float* x     = (const float*)d_in[0];
  const float* V1    = (const float*)d_in[1];
  const float* a1    = (const float*)d_in[2];
  const float* root1 = (const float*)d_in[3];
  const float* bias1 = (const float*)d_in[4];
  const float* V2    = (const float*)d_in[5];
  const float* a2    = (const float*)d_in[6];
  const float* root2 = (const float*)d_in[7];
  const float* bias2 = (const float*)d_in[8];
  const int*   ei    = (const int*)d_in[9];    // [2, E]
  const int*   et    = (const int*)d_in[10];   // [E]

  const int N = in_sizes[0] / TD;
  const int E = in_sizes[10];
  const int R = 32;

  char* w = (char*)d_ws;
  auto alloc = [&](size_t bytes) {
    char* p = w;
    w += (bytes + 255) & ~(size_t)255;
    return p;
  };
  int*   off    = (int*)alloc((size_t)(N + 1) * 4);
  int*   cursor = (int*)alloc((size_t)N * 4);
  int*   deg    = (int*)alloc((size_t)N * 4);
  int*   cnt2   = (int*)alloc((size_t)R * N * 4);
  int*   packed = (int*)alloc((size_t)E * 4);
  float* invc   = (float*)alloc((size_t)E * 4);
  float* h      = (float*)alloc((size_t)N * TD * 4);

  hipMemsetAsync(deg, 0, (size_t)N * 4, stream);
  hipMemsetAsync(cnt2, 0, (size_t)R * N * 4, stream);

  int egrid = (E + 255) / 256;
  k_hist<<<egrid, 256, 0, stream>>>(ei, et, deg, cnt2, E, N);
  k_scan<<<1, 1024, 0, stream>>>(deg, off, cursor, N, E);
  k_scatter<<<egrid, 256, 0, stream>>>(ei, et, cursor, cnt2, packed, invc, E, N);

  const size_t shmem = (size_t)(TNB * ZSTR + TNB * XSTR + 256) * sizeof(float);
  hipFuncSetAttribute(reinterpret_cast<const void*>(&k_layer<128, true, false>),
                      hipFuncAttributeMaxDynamicSharedMemorySize, (int)shmem);
  hipFuncSetAttribute(reinterpret_cast<const void*>(&k_layer<32, false, true>),
                      hipFuncAttributeMaxDynamicSharedMemorySize, (int)shmem);

  int ngrid = (N + TNB - 1) / TNB;
  k_layer<128, true, false><<<ngrid, BLK, shmem, stream>>>(
      x, V1, a1, root1, bias1, off, packed, invc, h, N);
  k_layer<32, false, true><<<ngrid, BLK, shmem, stream>>>(
      h, V2, a2, root2, bias2, off, packed, invc, (float*)d_out, N);
}

// Round 3
// 579.712 us; speedup vs baseline: 3.3625x; 2.4807x over previous
//
#include <hip/hip_runtime.h>
#include <hip/hip_bf16.h>

// RGCN 2-layer, basis-decomposed.
// R2: phase-2 GEMM via MFMA 16x16x32 bf16 with split-bf16 (hi/lo) 3-term trick.
// Phase 1 (edge aggregation) stays f32, writes z as bf16 hi/lo into LDS.

typedef __attribute__((ext_vector_type(8))) short bf16x8;
typedef __attribute__((ext_vector_type(4))) float f32x4;
typedef unsigned short u16;

constexpr int TD   = 128;        // feature dim (both layers' input dim)
constexpr int TB   = 8;          // bases
constexpr int TK   = TB * TD;    // 1024
constexpr int TNB  = 16;         // nodes per block
constexpr int BLK  = 512;        // 8 waves
constexpr int ZK   = TK + 8;     // ushort stride for z rows (2064 B: bank-spread)
constexpr int XK   = TD + 8;     // ushort stride for x rows

__device__ inline void splitbf(float v, u16& h, u16& l) {
  unsigned int u = __float_as_uint(v);
  unsigned int r = u + 0x7FFF + ((u >> 16) & 1);   // rne to bf16
  u16 hb = (u16)(r >> 16);
  float hv = __uint_as_float((unsigned int)hb << 16);
  float lo = v - hv;
  unsigned int u2 = __float_as_uint(lo);
  unsigned int r2 = u2 + 0x7FFF + ((u2 >> 16) & 1);
  h = hb;
  l = (u16)(r2 >> 16);
}

// transpose + hi/lo split the weight matrices: W[k][o] -> WT_hi/lo[o][k]
__global__ void k_prep(const float* __restrict__ V1, const float* __restrict__ root1,
                       const float* __restrict__ V2, const float* __restrict__ root2,
                       u16* __restrict__ v1th, u16* __restrict__ v1tl,
                       u16* __restrict__ r1th, u16* __restrict__ r1tl,
                       u16* __restrict__ v2th, u16* __restrict__ v2tl,
                       u16* __restrict__ r2th, u16* __restrict__ r2tl) {
  int idx = blockIdx.x * 256 + threadIdx.x;
  if (idx < 128 * 1024) splitbf(V1[(size_t)(idx & 1023) * 128 + (idx >> 10)], v1th[idx], v1tl[idx]);
  if (idx < 128 * 128)  splitbf(root1[(size_t)(idx & 127) * 128 + (idx >> 7)], r1th[idx], r1tl[idx]);
  if (idx < 32 * 1024)  splitbf(V2[(size_t)(idx & 1023) * 32 + (idx >> 10)], v2th[idx], v2tl[idx]);
  if (idx < 32 * 128)   splitbf(root2[(size_t)(idx & 127) * 32 + (idx >> 7)], r2th[idx], r2tl[idx]);
}

__global__ void k_hist(const int* __restrict__ ei, const int* __restrict__ et,
                       int* __restrict__ deg, int* __restrict__ cnt2,
                       int E, int N) {
  int e = blockIdx.x * 256 + threadIdx.x;
  if (e >= E) return;
  int d = ei[E + e];
  int r = et[e];
  atomicAdd(&deg[d], 1);
  atomicAdd(&cnt2[r * N + d], 1);
}

// single-block exclusive prefix sum (wave-shuffle based)
__global__ void k_scan(const int* __restrict__ deg, int* __restrict__ off,
                       int* __restrict__ cursor, int n, int total) {
  __shared__ int wsum[16];
  __shared__ int carry_s;
  const int t = threadIdx.x, lane = t & 63, w = t >> 6;
  if (t == 0) carry_s = 0;
  __syncthreads();
  for (int base = 0; base < n; base += 1024) {
    int i = base + t;
    int v = (i < n) ? deg[i] : 0;
    int s = v;
#pragma unroll
    for (int d = 1; d < 64; d <<= 1) {
      int u = __shfl_up(s, d);
      if (lane >= d) s += u;
    }
    if (lane == 63) wsum[w] = s;
    __syncthreads();
    if (w == 0) {
      int ws = (lane < 16) ? wsum[lane] : 0;
#pragma unroll
      for (int d = 1; d < 16; d <<= 1) {
        int u = __shfl_up(ws, d);
        if (lane >= d) ws += u;
      }
      if (lane < 16) wsum[lane] = ws;
    }
    __syncthreads();
    int wbase = (w == 0) ? 0 : wsum[w - 1];
    int carry = carry_s;
    if (i < n) { int ex = carry + wbase + s - v; off[i] = ex; cursor[i] = ex; }
    __syncthreads();
    if (t == 1023) carry_s = carry + wbase + s;
    __syncthreads();
  }
  if (t == 0) off[n] = total;
}

__global__ void k_scatter(const int* __restrict__ ei, const int* __restrict__ et,
                          int* __restrict__ cursor, const int* __restrict__ cnt2,
                          int* __restrict__ packed, float* __restrict__ invc,
                          int E, int N) {
  int e = blockIdx.x * 256 + threadIdx.x;
  if (e >= E) return;
  int s = ei[e], d = ei[E + e], r = et[e];
  int p = atomicAdd(&cursor[d], 1);
  packed[p] = s | (r << 17);
  invc[p] = 1.0f / (float)cnt2[r * N + d];
}

#define MFMA16(A, B, C) __builtin_amdgcn_mfma_f32_16x16x32_bf16((A), (B), (C), 0, 0, 0)

template <int DOUT, bool RELU, bool SOFTMAX>
__global__ __launch_bounds__(BLK, 4) void k_layer(
    const float* __restrict__ in,
    const u16* __restrict__ wth, const u16* __restrict__ wtl,    // [DOUT][TK]
    const float* __restrict__ a,
    const u16* __restrict__ rth, const u16* __restrict__ rtl,    // [DOUT][TD]
    const float* __restrict__ bias, const int* __restrict__ off,
    const int* __restrict__ packed, const float* __restrict__ invc,
    float* __restrict__ out, int Ntot) {
  extern __shared__ char smem[];
  u16* zh = (u16*)smem;                 // [TNB][ZK]
  u16* zl = zh + TNB * ZK;
  u16* xh = zl + TNB * ZK;              // [TNB][XK]
  u16* xl2 = xh + TNB * XK;
  float* ash = (float*)(xl2 + TNB * XK);  // [256] = a[R][B]
  const int t = threadIdx.x;
  const int n0 = blockIdx.x * TNB;

  if (t < 256) ash[t] = a[t];
  // stage x tile as hi/lo (used for root-term MFMA)
  {
    int row = t >> 5;
    int c4 = (t & 31) * 4;
    int n = n0 + row;
    float4 v = make_float4(0.f, 0.f, 0.f, 0.f);
    if (n < Ntot) v = *reinterpret_cast<const float4*>(in + (size_t)n * TD + c4);
    u16 h0, l0;
    splitbf(v.x, h0, l0); xh[row * XK + c4]     = h0; xl2[row * XK + c4]     = l0;
    splitbf(v.y, h0, l0); xh[row * XK + c4 + 1] = h0; xl2[row * XK + c4 + 1] = l0;
    splitbf(v.z, h0, l0); xh[row * XK + c4 + 2] = h0; xl2[row * XK + c4 + 2] = l0;
    splitbf(v.w, h0, l0); xh[row * XK + c4 + 3] = h0; xl2[row * XK + c4 + 3] = l0;
  }
  __syncthreads();

  // ---- phase 1: per-wave edge aggregation into z (2 nodes / wave) ----
  {
    const int wv = t >> 6, lane = t & 63;
    for (int nn = wv * 2; nn < wv * 2 + 2; ++nn) {
      int n = n0 + nn;
      float zacc[16];
#pragma unroll
      for (int j = 0; j < 16; ++j) zacc[j] = 0.f;
      if (n < Ntot) {
        int e = off[n], e1 = off[n + 1];
        for (; e + 2 <= e1; e += 2) {
          int pk0 = packed[e], pk1 = packed[e + 1];
          float iv0 = invc[e], iv1 = invc[e + 1];
          int s0 = pk0 & 131071, r0 = pk0 >> 17;
          int s1 = pk1 & 131071, r1 = pk1 >> 17;
          float x00 = in[(size_t)s0 * TD + lane];
          float x01 = in[(size_t)s0 * TD + 64 + lane];
          float x10 = in[(size_t)s1 * TD + lane];
          float x11 = in[(size_t)s1 * TD + 64 + lane];
          const float* ar0 = ash + r0 * TB;
          const float* ar1 = ash + r1 * TB;
#pragma unroll
          for (int b = 0; b < TB; ++b) {
            float c0 = ar0[b] * iv0;
            float c1 = ar1[b] * iv1;
            zacc[2 * b]     += c0 * x00;
            zacc[2 * b + 1] += c0 * x01;
            zacc[2 * b]     += c1 * x10;
            zacc[2 * b + 1] += c1 * x11;
          }
        }
        if (e < e1) {
          int pk = packed[e];
          float iv = invc[e];
          int s = pk & 131071, r = pk >> 17;
          float xv0 = in[(size_t)s * TD + lane];
          float xv1 = in[(size_t)s * TD + 64 + lane];
          const float* ar = ash + r * TB;
#pragma unroll
          for (int b = 0; b < TB; ++b) {
            float c = ar[b] * iv;
            zacc[2 * b]     += c * xv0;
            zacc[2 * b + 1] += c * xv1;
          }
        }
      }
#pragma unroll
      for (int b = 0; b < TB; ++b) {
        u16 h0, l0, h1, l1;
        splitbf(zacc[2 * b], h0, l0);
        splitbf(zacc[2 * b + 1], h1, l1);
        zh[nn * ZK + b * TD + lane]      = h0;
        zl[nn * ZK + b * TD + lane]      = l0;
        zh[nn * ZK + b * TD + 64 + lane] = h1;
        zl[nn * ZK + b * TD + 64 + lane] = l1;
      }
    }
  }
  __syncthreads();

  // ---- phase 2: MFMA GEMM [16, 1024+128] x [K, DOUT] ----
  const int w = t >> 6, lane = t & 63;
  const int mc = lane & 15, kg = lane >> 4;

  if constexpr (DOUT == 128) {
    // one 16-col n-tile per wave, all 36 k-steps
    f32x4 acc = {0.f, 0.f, 0.f, 0.f};
    {
      const u16* za = zh + mc * ZK + kg * 8;
      const u16* zb = zl + mc * ZK + kg * 8;
      const u16* bha = wth + (size_t)(w * 16 + mc) * TK + kg * 8;
      const u16* bla = wtl + (size_t)(w * 16 + mc) * TK + kg * 8;
#pragma unroll 4
      for (int ks = 0; ks < 32; ++ks) {
        bf16x8 ah  = *(const bf16x8*)(za + 32 * ks);
        bf16x8 alo = *(const bf16x8*)(zb + 32 * ks);
        bf16x8 bh  = *(const bf16x8*)(bha + 32 * ks);
        bf16x8 blo = *(const bf16x8*)(bla + 32 * ks);
        acc = MFMA16(ah, bh, acc);
        acc = MFMA16(alo, bh, acc);
        acc = MFMA16(ah, blo, acc);
      }
      const u16* xa = xh + mc * XK + kg * 8;
      const u16* xb = xl2 + mc * XK + kg * 8;
      const u16* rha = rth + (size_t)(w * 16 + mc) * TD + kg * 8;
      const u16* rla = rtl + (size_t)(w * 16 + mc) * TD + kg * 8;
#pragma unroll
      for (int ks = 0; ks < 4; ++ks) {
        bf16x8 ah  = *(const bf16x8*)(xa + 32 * ks);
        bf16x8 alo = *(const bf16x8*)(xb + 32 * ks);
        bf16x8 bh  = *(const bf16x8*)(rha + 32 * ks);
        bf16x8 blo = *(const bf16x8*)(rla + 32 * ks);
        acc = MFMA16(ah, bh, acc);
        acc = MFMA16(alo, bh, acc);
        acc = MFMA16(ah, blo, acc);
      }
    }
    float bb = bias[w * 16 + mc];
#pragma unroll
    for (int j = 0; j < 4; ++j) {
      int n = n0 + kg * 4 + j;
      if (n < Ntot) {
        float v = acc[j] + bb;
        if (RELU) v = fmaxf(v, 0.f);
        out[(size_t)n * 128 + w * 16 + mc] = v;
      }
    }
  } else {
    // DOUT == 32: 8-way K-split across waves, both col tiles per wave
    f32x4 a0 = {0.f, 0.f, 0.f, 0.f}, a1 = {0.f, 0.f, 0.f, 0.f};
    {
      const u16* za = zh + mc * ZK + kg * 8;
      const u16* zb = zl + mc * ZK + kg * 8;
      const u16* b0h = wth + (size_t)mc * TK + kg * 8;
      const u16* b0l = wtl + (size_t)mc * TK + kg * 8;
      const u16* b1h = wth + (size_t)(16 + mc) * TK + kg * 8;
      const u16* b1l = wtl + (size_t)(16 + mc) * TK + kg * 8;
#pragma unroll
      for (int i = 0; i < 4; ++i) {
        int ks = w * 4 + i;
        bf16x8 ah  = *(const bf16x8*)(za + 32 * ks);
        bf16x8 alo = *(const bf16x8*)(zb + 32 * ks);
        bf16x8 bh0 = *(const bf16x8*)(b0h + 32 * ks);
        bf16x8 bl0 = *(const bf16x8*)(b0l + 32 * ks);
        bf16x8 bh1 = *(const bf16x8*)(b1h + 32 * ks);
        bf16x8 bl1 = *(const bf16x8*)(b1l + 32 * ks);
        a0 = MFMA16(ah, bh0, a0);
        a0 = MFMA16(alo, bh0, a0);
        a0 = MFMA16(ah, bl0, a0);
        a1 = MFMA16(ah, bh1, a1);
        a1 = MFMA16(alo, bh1, a1);
        a1 = MFMA16(ah, bl1, a1);
      }
      if (w < 4) {
        int ks = w;
        bf16x8 ah  = *(const bf16x8*)(xh + mc * XK + kg * 8 + 32 * ks);
        bf16x8 alo = *(const bf16x8*)(xl2 + mc * XK + kg * 8 + 32 * ks);
        bf16x8 bh0 = *(const bf16x8*)(rth + (size_t)mc * TD + kg * 8 + 32 * ks);
        bf16x8 bl0 = *(const bf16x8*)(rtl + (size_t)mc * TD + kg * 8 + 32 * ks);
        bf16x8 bh1 = *(const bf16x8*)(rth + (size_t)(16 + mc) * TD + kg * 8 + 32 * ks);
        bf16x8 bl1 = *(const bf16x8*)(rtl + (size_t)(16 + mc) * TD + kg * 8 + 32 * ks);
        a0 = MFMA16(ah, bh0, a0);
        a0 = MFMA16(alo, bh0, a0);
        a0 = MFMA16(ah, bl0, a0);
        a1 = MFMA16(ah, bh1, a1);
        a1 = MFMA16(alo, bh1, a1);
        a1 = MFMA16(ah, bl1, a1);
      }
    }
    __syncthreads();                       // all z reads done
    float* pc = (float*)smem;              // [8 waves][2 tiles][256] partials
#pragma unroll
    for (int j = 0; j < 4; ++j) {
      pc[(w * 2 + 0) * 256 + (kg * 4 + j) * 16 + mc] = a0[j];
      pc[(w * 2 + 1) * 256 + (kg * 4 + j) * 16 + mc] = a1[j];
    }
    __syncthreads();
    int row = t >> 5, col = t & 31;
    int tile = col >> 4, cc = col & 15;
    float v = 0.f;
#pragma unroll
    for (int ww = 0; ww < 8; ++ww) v += pc[(ww * 2 + tile) * 256 + row * 16 + cc];
    v += bias[col];
    if constexpr (SOFTMAX) {
      float m = v;
      m = fmaxf(m, __shfl_xor(m, 1));
      m = fmaxf(m, __shfl_xor(m, 2));
      m = fmaxf(m, __shfl_xor(m, 4));
      m = fmaxf(m, __shfl_xor(m, 8));
      m = fmaxf(m, __shfl_xor(m, 16));
      float ev = __expf(v - m);
      float s = ev;
      s += __shfl_xor(s, 1); s += __shfl_xor(s, 2); s += __shfl_xor(s, 4);
      s += __shfl_xor(s, 8); s += __shfl_xor(s, 16);
      v = ev / s;
    }
    int n = n0 + row;
    if (n < Ntot) out[(size_t)n * 32 + col] = v;
  }
}

extern "C" void kernel_launch(void* const* d_in, const int* in_sizes, int n_in,
                              void* d_out, int out_size, void* d_ws, size_t ws_size,
                              hipStream_t stream) {
  const float* x     = (const float*)d_in[0];
  const float* V1    = (const float*)d_in[1];
  const float* a1    = (const float*)d_in[2];
  const float* root1 = (const float*)d_in[3];
  const float* bias1 = (const float*)d_in[4];
  const float* V2    = (const float*)d_in[5];
  const float* a2    = (const float*)d_in[6];
  const float* root2 = (const float*)d_in[7];
  const float* bias2 = (const float*)d_in[8];
  const int*   ei    = (const int*)d_in[9];    // [2, E]
  const int*   et    = (const int*)d_in[10];   // [E]

  const int N = in_sizes[0] / TD;
  const int E = in_sizes[10];
  const int R = 32;

  char* w = (char*)d_ws;
  auto alloc = [&](size_t bytes) {
    char* p = w;
    w += (bytes + 255) & ~(size_t)255;
    return p;
  };
  int*   off    = (int*)alloc((size_t)(N + 1) * 4);
  int*   cursor = (int*)alloc((size_t)N * 4);
  int*   deg    = (int*)alloc((size_t)N * 4);
  int*   cnt2   = (int*)alloc((size_t)R * N * 4);
  int*   packed = (int*)alloc((size_t)E * 4);
  float* invc   = (float*)alloc((size_t)E * 4);
  float* h      = (float*)alloc((size_t)N * TD * 4);
  u16*   v1th   = (u16*)alloc((size_t)128 * 1024 * 2);
  u16*   v1tl   = (u16*)alloc((size_t)128 * 1024 * 2);
  u16*   r1th   = (u16*)alloc((size_t)128 * 128 * 2);
  u16*   r1tl   = (u16*)alloc((size_t)128 * 128 * 2);
  u16*   v2th   = (u16*)alloc((size_t)32 * 1024 * 2);
  u16*   v2tl   = (u16*)alloc((size_t)32 * 1024 * 2);
  u16*   r2th   = (u16*)alloc((size_t)32 * 128 * 2);
  u16*   r2tl   = (u16*)alloc((size_t)32 * 128 * 2);

  hipMemsetAsync(deg, 0, (size_t)N * 4, stream);
  hipMemsetAsync(cnt2, 0, (size_t)R * N * 4, stream);

  k_prep<<<512, 256, 0, stream>>>(V1, root1, V2, root2,
                                  v1th, v1tl, r1th, r1tl, v2th, v2tl, r2th, r2tl);

  int egrid = (E + 255) / 256;
  k_hist<<<egrid, 256, 0, stream>>>(ei, et, deg, cnt2, E, N);
  k_scan<<<1, 1024, 0, stream>>>(deg, off, cursor, N, E);
  k_scatter<<<egrid, 256, 0, stream>>>(ei, et, cursor, cnt2, packed, invc, E, N);

  const size_t shmem = (size_t)(2 * TNB * ZK + 2 * TNB * XK) * 2 + 256 * 4;
  hipFuncSetAttribute(reinterpret_cast<const void*>(&k_layer<128, true, false>),
                      hipFuncAttributeMaxDynamicSharedMemorySize, (int)shmem);
  hipFuncSetAttribute(reinterpret_cast<const void*>(&k_layer<32, false, true>),
                      hipFuncAttributeMaxDynamicSharedMemorySize, (int)shmem);

  int ngrid = (N + TNB - 1) / TNB;
  k_layer<128, true, false><<<ngrid, BLK, shmem, stream>>>(
      x, v1th, v1tl, a1, r1th, r1tl, bias1, off, packed, invc, h, N);
  k_layer<32, false, true><<<ngrid, BLK, shmem, stream>>>(
      h, v2th, v2tl, a2, r2th, r2tl, bias2, off, packed, invc, (float*)d_out, N);
}

// Round 7
// 564.575 us; speedup vs baseline: 3.4526x; 1.0268x over previous
//
#include <hip/hip_runtime.h>
#include <hip/hip_bf16.h>

// RGCN 2-layer, basis-decomposed.
// R6 = bisection: exact R2 kernel (verified pass, 579us) with ONLY phase 1
// replaced by the half-wave float4 gather pipeline. R2's LDS layout (ZK
// stride, no swizzle), scatter, x-staging, and phase 2 are untouched.

typedef __attribute__((ext_vector_type(8))) short bf16x8;
typedef __attribute__((ext_vector_type(4))) float f32x4;
typedef unsigned short u16;
typedef __attribute__((ext_vector_type(4))) unsigned short u16x4;

constexpr int TD   = 128;        // feature dim (both layers' input dim)
constexpr int TB   = 8;          // bases
constexpr int TK   = TB * TD;    // 1024
constexpr int TNB  = 16;         // nodes per block
constexpr int BLK  = 512;        // 8 waves
constexpr int ZK   = TK + 8;     // ushort stride for z rows (2064 B)
constexpr int XK   = TD + 8;     // ushort stride for x rows

// returns (hi, lo) bf16 pair packed: hi in low 16, lo in high 16
__device__ inline unsigned int splitbf(float v) {
  unsigned int u = __float_as_uint(v);
  unsigned int r = u + 0x7FFF + ((u >> 16) & 1);   // rne to bf16
  unsigned int hb = r >> 16;
  float hv = __uint_as_float(hb << 16);
  float lo = v - hv;
  unsigned int u2 = __float_as_uint(lo);
  unsigned int r2 = u2 + 0x7FFF + ((u2 >> 16) & 1);
  return (hb & 0xFFFFu) | (r2 & 0xFFFF0000u);
}

// W[k][o] -> WT_hi/lo[o][k]
__global__ void k_prep(const float* __restrict__ V1, const float* __restrict__ root1,
                       const float* __restrict__ V2, const float* __restrict__ root2,
                       u16* __restrict__ v1th, u16* __restrict__ v1tl,
                       u16* __restrict__ r1th, u16* __restrict__ r1tl,
                       u16* __restrict__ v2th, u16* __restrict__ v2tl,
                       u16* __restrict__ r2th, u16* __restrict__ r2tl) {
  int idx = blockIdx.x * 256 + threadIdx.x;
  if (idx < 128 * 1024) {
    unsigned int p = splitbf(V1[(size_t)(idx & 1023) * 128 + (idx >> 10)]);
    v1th[idx] = (u16)p; v1tl[idx] = (u16)(p >> 16);
  }
  if (idx < 128 * 128) {
    unsigned int p = splitbf(root1[(size_t)(idx & 127) * 128 + (idx >> 7)]);
    r1th[idx] = (u16)p; r1tl[idx] = (u16)(p >> 16);
  }
  if (idx < 32 * 1024) {
    unsigned int p = splitbf(V2[(size_t)(idx & 1023) * 32 + (idx >> 10)]);
    v2th[idx] = (u16)p; v2tl[idx] = (u16)(p >> 16);
  }
  if (idx < 32 * 128) {
    unsigned int p = splitbf(root2[(size_t)(idx & 127) * 32 + (idx >> 7)]);
    r2th[idx] = (u16)p; r2tl[idx] = (u16)(p >> 16);
  }
}

__global__ void k_hist(const int* __restrict__ ei, const int* __restrict__ et,
                       int* __restrict__ deg, int* __restrict__ cnt2,
                       int E, int N) {
  int e = blockIdx.x * 256 + threadIdx.x;
  if (e >= E) return;
  int d = ei[E + e];
  int r = et[e];
  atomicAdd(&deg[d], 1);
  atomicAdd(&cnt2[r * N + d], 1);
}

__global__ void k_scan(const int* __restrict__ deg, int* __restrict__ off,
                       int* __restrict__ cursor, int n, int total) {
  __shared__ int wsum[16];
  __shared__ int carry_s;
  const int t = threadIdx.x, lane = t & 63, w = t >> 6;
  if (t == 0) carry_s = 0;
  __syncthreads();
  for (int base = 0; base < n; base += 1024) {
    int i = base + t;
    int v = (i < n) ? deg[i] : 0;
    int s = v;
#pragma unroll
    for (int d = 1; d < 64; d <<= 1) {
      int u = __shfl_up(s, d);
      if (lane >= d) s += u;
    }
    if (lane == 63) wsum[w] = s;
    __syncthreads();
    if (w == 0) {
      int ws = (lane < 16) ? wsum[lane] : 0;
#pragma unroll
      for (int d = 1; d < 16; d <<= 1) {
        int u = __shfl_up(ws, d);
        if (lane >= d) ws += u;
      }
      if (lane < 16) wsum[lane] = ws;
    }
    __syncthreads();
    int wbase = (w == 0) ? 0 : wsum[w - 1];
    int carry = carry_s;
    if (i < n) { int ex = carry + wbase + s - v; off[i] = ex; cursor[i] = ex; }
    __syncthreads();
    if (t == 1023) carry_s = carry + wbase + s;
    __syncthreads();
  }
  if (t == 0) off[n] = total;
}

__global__ void k_scatter(const int* __restrict__ ei, const int* __restrict__ et,
                          int* __restrict__ cursor, const int* __restrict__ cnt2,
                          int* __restrict__ packed, float* __restrict__ invc,
                          int E, int N) {
  int e = blockIdx.x * 256 + threadIdx.x;
  if (e >= E) return;
  int s = ei[e], d = ei[E + e], r = et[e];
  int p = atomicAdd(&cursor[d], 1);
  packed[p] = s | (r << 17);
  invc[p] = 1.0f / (float)cnt2[r * N + d];
}

#define MFMA16(A, B, C) __builtin_amdgcn_mfma_f32_16x16x32_bf16((A), (B), (C), 0, 0, 0)

template <int DOUT, bool RELU, bool SOFTMAX>
__global__ __launch_bounds__(BLK, 4) void k_layer(
    const float* __restrict__ in,
    const u16* __restrict__ wth, const u16* __restrict__ wtl,    // [DOUT][TK]
    const float* __restrict__ a,
    const u16* __restrict__ rth, const u16* __restrict__ rtl,    // [DOUT][TD]
    const float* __restrict__ bias, const int* __restrict__ off,
    const int* __restrict__ packed, const float* __restrict__ invc,
    float* __restrict__ out, int Ntot) {
  extern __shared__ char smem[];
  u16* zh = (u16*)smem;                 // [TNB][ZK]
  u16* zl = zh + TNB * ZK;
  u16* xh = zl + TNB * ZK;              // [TNB][XK]
  u16* xl2 = xh + TNB * XK;
  float* ash = (float*)(xl2 + TNB * XK);  // [256] = a[R][B]
  const int t = threadIdx.x;
  const int n0 = blockIdx.x * TNB;

  if (t < 256) ash[t] = a[t];
  // stage x tile as hi/lo (R2-exact)
  {
    int row = t >> 5;
    int c4 = (t & 31) * 4;
    int n = n0 + row;
    float4 v = make_float4(0.f, 0.f, 0.f, 0.f);
    if (n < Ntot) v = *reinterpret_cast<const float4*>(in + (size_t)n * TD + c4);
    unsigned int p0 = splitbf(v.x), p1 = splitbf(v.y), p2 = splitbf(v.z), p3 = splitbf(v.w);
    xh[row * XK + c4]     = (u16)p0; xl2[row * XK + c4]     = (u16)(p0 >> 16);
    xh[row * XK + c4 + 1] = (u16)p1; xl2[row * XK + c4 + 1] = (u16)(p1 >> 16);
    xh[row * XK + c4 + 2] = (u16)p2; xl2[row * XK + c4 + 2] = (u16)(p2 >> 16);
    xh[row * XK + c4 + 3] = (u16)p3; xl2[row * XK + c4 + 3] = (u16)(p3 >> 16);
  }
  __syncthreads();

  // ---- phase 1: half-wave-per-edge float4 gather, 2-deep ping-pong ----
  {
    const int wv = t >> 6, lane = t & 63;
    const int hf = lane >> 5, q = lane & 31;

    for (int nn = wv * 2; nn < wv * 2 + 2; ++nn) {
      int n = n0 + nn;
      float acc[8][4];
#pragma unroll
      for (int b = 0; b < 8; ++b)
#pragma unroll
        for (int j = 0; j < 4; ++j) acc[b][j] = 0.f;

      if (n < Ntot) {
        int e0 = off[n], e1 = off[n + 1];
        int np = (e1 - e0 + 1) >> 1;

        struct Pk { float4 xv, c0, c1; };
        auto ldst = [&](int pe) {
          Pk P;
          int e = e0 + 2 * pe + hf;
          float iv = 0.f; int r = 0;
          P.xv = make_float4(0.f, 0.f, 0.f, 0.f);
          if (e < e1) {
            int pk = packed[e];
            iv = invc[e];
            r = pk >> 17;
            P.xv = *reinterpret_cast<const float4*>(in + (size_t)(pk & 131071) * TD + q * 4);
          }
          float4 t0 = *reinterpret_cast<const float4*>(ash + r * 8);
          float4 t1 = *reinterpret_cast<const float4*>(ash + r * 8 + 4);
          P.c0 = make_float4(t0.x * iv, t0.y * iv, t0.z * iv, t0.w * iv);
          P.c1 = make_float4(t1.x * iv, t1.y * iv, t1.z * iv, t1.w * iv);
          return P;
        };
        auto comp = [&](const Pk& P) {
#define ACCB(bi, cc) \
          acc[bi][0] += (cc) * P.xv.x; acc[bi][1] += (cc) * P.xv.y; \
          acc[bi][2] += (cc) * P.xv.z; acc[bi][3] += (cc) * P.xv.w;
          ACCB(0, P.c0.x) ACCB(1, P.c0.y) ACCB(2, P.c0.z) ACCB(3, P.c0.w)
          ACCB(4, P.c1.x) ACCB(5, P.c1.y) ACCB(6, P.c1.z) ACCB(7, P.c1.w)
#undef ACCB
        };

        Pk A, B;
        if (np > 0) A = ldst(0);
        if (np > 1) B = ldst(1);
        for (int pe = 0; pe < np; pe += 2) {
          comp(A);
          if (pe + 2 < np) A = ldst(pe + 2);
          if (pe + 1 < np) {
            comp(B);
            if (pe + 3 < np) B = ldst(pe + 3);
          }
        }
      }

      // cross-half reduce; hf==0 lanes write BOTH hi and lo (same source value)
#pragma unroll
      for (int b = 0; b < 8; ++b) {
        float v0 = acc[b][0] + __shfl_xor(acc[b][0], 32);
        float v1 = acc[b][1] + __shfl_xor(acc[b][1], 32);
        float v2 = acc[b][2] + __shfl_xor(acc[b][2], 32);
        float v3 = acc[b][3] + __shfl_xor(acc[b][3], 32);
        if (hf == 0) {
          unsigned int p0 = splitbf(v0), p1 = splitbf(v1), p2 = splitbf(v2), p3 = splitbf(v3);
          u16x4 hh, ll;
          hh[0] = (u16)p0; ll[0] = (u16)(p0 >> 16);
          hh[1] = (u16)p1; ll[1] = (u16)(p1 >> 16);
          hh[2] = (u16)p2; ll[2] = (u16)(p2 >> 16);
          hh[3] = (u16)p3; ll[3] = (u16)(p3 >> 16);
          int idx = nn * ZK + b * TD + q * 4;
          *reinterpret_cast<u16x4*>(zh + idx) = hh;
          *reinterpret_cast<u16x4*>(zl + idx) = ll;
        }
      }
    }
  }
  __syncthreads();

  // ---- phase 2: MFMA GEMM (R2-exact) ----
  const int w = t >> 6, lane = t & 63;
  const int mc = lane & 15, kg = lane >> 4;

  if constexpr (DOUT == 128) {
    f32x4 acc = {0.f, 0.f, 0.f, 0.f};
    {
      const u16* za = zh + mc * ZK + kg * 8;
      const u16* zb = zl + mc * ZK + kg * 8;
      const u16* bha = wth + (size_t)(w * 16 + mc) * TK + kg * 8;
      const u16* bla = wtl + (size_t)(w * 16 + mc) * TK + kg * 8;
#pragma unroll 4
      for (int ks = 0; ks < 32; ++ks) {
        bf16x8 ah  = *(const bf16x8*)(za + 32 * ks);
        bf16x8 alo = *(const bf16x8*)(zb + 32 * ks);
        bf16x8 bh  = *(const bf16x8*)(bha + 32 * ks);
        bf16x8 blo = *(const bf16x8*)(bla + 32 * ks);
        acc = MFMA16(ah, bh, acc);
        acc = MFMA16(alo, bh, acc);
        acc = MFMA16(ah, blo, acc);
      }
      const u16* xa = xh + mc * XK + kg * 8;
      const u16* xb = xl2 + mc * XK + kg * 8;
      const u16* rha = rth + (size_t)(w * 16 + mc) * TD + kg * 8;
      const u16* rla = rtl + (size_t)(w * 16 + mc) * TD + kg * 8;
#pragma unroll
      for (int ks = 0; ks < 4; ++ks) {
        bf16x8 ah  = *(const bf16x8*)(xa + 32 * ks);
        bf16x8 alo = *(const bf16x8*)(xb + 32 * ks);
        bf16x8 bh  = *(const bf16x8*)(rha + 32 * ks);
        bf16x8 blo = *(const bf16x8*)(rla + 32 * ks);
        acc = MFMA16(ah, bh, acc);
        acc = MFMA16(alo, bh, acc);
        acc = MFMA16(ah, blo, acc);
      }
    }
    float bb = bias[w * 16 + mc];
#pragma unroll
    for (int j = 0; j < 4; ++j) {
      int n = n0 + kg * 4 + j;
      if (n < Ntot) {
        float v = acc[j] + bb;
        if (RELU) v = fmaxf(v, 0.f);
        out[(size_t)n * 128 + w * 16 + mc] = v;
      }
    }
  } else {
    // DOUT == 32: 8-way K-split across waves, both col tiles per wave
    f32x4 a0 = {0.f, 0.f, 0.f, 0.f}, a1 = {0.f, 0.f, 0.f, 0.f};
    {
      const u16* za = zh + mc * ZK + kg * 8;
      const u16* zb = zl + mc * ZK + kg * 8;
      const u16* b0h = wth + (size_t)mc * TK + kg * 8;
      const u16* b0l = wtl + (size_t)mc * TK + kg * 8;
      const u16* b1h = wth + (size_t)(16 + mc) * TK + kg * 8;
      const u16* b1l = wtl + (size_t)(16 + mc) * TK + kg * 8;
#pragma unroll
      for (int i = 0; i < 4; ++i) {
        int ks = w * 4 + i;
        bf16x8 ah  = *(const bf16x8*)(za + 32 * ks);
        bf16x8 alo = *(const bf16x8*)(zb + 32 * ks);
        bf16x8 bh0 = *(const bf16x8*)(b0h + 32 * ks);
        bf16x8 bl0 = *(const bf16x8*)(b0l + 32 * ks);
        bf16x8 bh1 = *(const bf16x8*)(b1h + 32 * ks);
        bf16x8 bl1 = *(const bf16x8*)(b1l + 32 * ks);
        a0 = MFMA16(ah, bh0, a0);
        a0 = MFMA16(alo, bh0, a0);
        a0 = MFMA16(ah, bl0, a0);
        a1 = MFMA16(ah, bh1, a1);
        a1 = MFMA16(alo, bh1, a1);
        a1 = MFMA16(ah, bl1, a1);
      }
      if (w < 4) {
        int ks = w;
        bf16x8 ah  = *(const bf16x8*)(xh + mc * XK + kg * 8 + 32 * ks);
        bf16x8 alo = *(const bf16x8*)(xl2 + mc * XK + kg * 8 + 32 * ks);
        bf16x8 bh0 = *(const bf16x8*)(rth + (size_t)mc * TD + kg * 8 + 32 * ks);
        bf16x8 bl0 = *(const bf16x8*)(rtl + (size_t)mc * TD + kg * 8 + 32 * ks);
        bf16x8 bh1 = *(const bf16x8*)(rth + (size_t)(16 + mc) * TD + kg * 8 + 32 * ks);
        bf16x8 bl1 = *(const bf16x8*)(rtl + (size_t)(16 + mc) * TD + kg * 8 + 32 * ks);
        a0 = MFMA16(ah, bh0, a0);
        a0 = MFMA16(alo, bh0, a0);
        a0 = MFMA16(ah, bl0, a0);
        a1 = MFMA16(ah, bh1, a1);
        a1 = MFMA16(alo, bh1, a1);
        a1 = MFMA16(ah, bl1, a1);
      }
    }
    __syncthreads();                       // all z reads done
    float* pc = (float*)smem;              // [8 waves][2 tiles][256] partials
#pragma unroll
    for (int j = 0; j < 4; ++j) {
      pc[(w * 2 + 0) * 256 + (kg * 4 + j) * 16 + mc] = a0[j];
      pc[(w * 2 + 1) * 256 + (kg * 4 + j) * 16 + mc] = a1[j];
    }
    __syncthreads();
    int row = t >> 5, col = t & 31;
    int tile = col >> 4, cc = col & 15;
    float v = 0.f;
#pragma unroll
    for (int ww = 0; ww < 8; ++ww) v += pc[(ww * 2 + tile) * 256 + row * 16 + cc];
    v += bias[col];
    if constexpr (SOFTMAX) {
      float m = v;
      m = fmaxf(m, __shfl_xor(m, 1));
      m = fmaxf(m, __shfl_xor(m, 2));
      m = fmaxf(m, __shfl_xor(m, 4));
      m = fmaxf(m, __shfl_xor(m, 8));
      m = fmaxf(m, __shfl_xor(m, 16));
      float ev = __expf(v - m);
      float s = ev;
      s += __shfl_xor(s, 1); s += __shfl_xor(s, 2); s += __shfl_xor(s, 4);
      s += __shfl_xor(s, 8); s += __shfl_xor(s, 16);
      v = ev / s;
    }
    int n = n0 + row;
    if (n < Ntot) out[(size_t)n * 32 + col] = v;
  }
}

extern "C" void kernel_launch(void* const* d_in, const int* in_sizes, int n_in,
                              void* d_out, int out_size, void* d_ws, size_t ws_size,
                              hipStream_t stream) {
  const float* x     = (const float*)d_in[0];
  const float* V1    = (const float*)d_in[1];
  const float* a1    = (const float*)d_in[2];
  const float* root1 = (const float*)d_in[3];
  const float* bias1 = (const float*)d_in[4];
  const float* V2    = (const float*)d_in[5];
  const float* a2    = (const float*)d_in[6];
  const float* root2 = (const float*)d_in[7];
  const float* bias2 = (const float*)d_in[8];
  const int*   ei    = (const int*)d_in[9];    // [2, E]
  const int*   et    = (const int*)d_in[10];   // [E]

  const int N = in_sizes[0] / TD;
  const int E = in_sizes[10];
  const int R = 32;

  char* w = (char*)d_ws;
  auto alloc = [&](size_t bytes) {
    char* p = w;
    w += (bytes + 255) & ~(size_t)255;
    return p;
  };
  int*   off    = (int*)alloc((size_t)(N + 1) * 4);
  int*   cursor = (int*)alloc((size_t)N * 4);
  int*   deg    = (int*)alloc((size_t)N * 4);
  int*   cnt2   = (int*)alloc((size_t)R * N * 4);
  int*   packed = (int*)alloc((size_t)E * 4);
  float* invc   = (float*)alloc((size_t)E * 4);
  float* h      = (float*)alloc((size_t)N * TD * 4);
  u16*   v1th   = (u16*)alloc((size_t)128 * 1024 * 2);
  u16*   v1tl   = (u16*)alloc((size_t)128 * 1024 * 2);
  u16*   r1th   = (u16*)alloc((size_t)128 * 128 * 2);
  u16*   r1tl   = (u16*)alloc((size_t)128 * 128 * 2);
  u16*   v2th   = (u16*)alloc((size_t)32 * 1024 * 2);
  u16*   v2tl   = (u16*)alloc((size_t)32 * 1024 * 2);
  u16*   r2th   = (u16*)alloc((size_t)32 * 128 * 2);
  u16*   r2tl   = (u16*)alloc((size_t)32 * 128 * 2);

  hipMemsetAsync(deg, 0, (size_t)N * 4, stream);
  hipMemsetAsync(cnt2, 0, (size_t)R * N * 4, stream);

  k_prep<<<512, 256, 0, stream>>>(V1, root1, V2, root2,
                                  v1th, v1tl, r1th, r1tl, v2th, v2tl, r2th, r2tl);

  int egrid = (E + 255) / 256;
  k_hist<<<egrid, 256, 0, stream>>>(ei, et, deg, cnt2, E, N);
  k_scan<<<1, 1024, 0, stream>>>(deg, off, cursor, N, E);
  k_scatter<<<egrid, 256, 0, stream>>>(ei, et, cursor, cnt2, packed, invc, E, N);

  const size_t shmem = (size_t)(2 * TNB * ZK + 2 * TNB * XK) * 2 + 256 * 4;
  (void)hipFuncSetAttribute(reinterpret_cast<const void*>(&k_layer<128, true, false>),
                            hipFuncAttributeMaxDynamicSharedMemorySize, (int)shmem);
  (void)hipFuncSetAttribute(reinterpret_cast<const void*>(&k_layer<32, false, true>),
                            hipFuncAttributeMaxDynamicSharedMemorySize, (int)shmem);

  int ngrid = (N + TNB - 1) / TNB;
  k_layer<128, true, false><<<ngrid, BLK, shmem, stream>>>(
      x, v1th, v1tl, a1, r1th, r1tl, bias1, off, packed, invc, h, N);
  k_layer<32, false, true><<<ngrid, BLK, shmem, stream>>>(
      h, v2th, v2tl, a2, r2th, r2tl, bias2, off, packed, invc, (float*)d_out, N);
}